// Round 1
// baseline (676.488 us; speedup 1.0000x reference)
//
#include <hip/hip_runtime.h>
#include <math.h>

// Problem constants (fixed by the reference)
#define Nn 4096
#define Mm 4096
#define Dd 512
#define NP 4097            // N+1 == M+1 (augmented with dustbin)

// phi = REG_KL / (REG_KL + REG) = 0.01/0.11 ; lmba = 10
#define PHI 0.09090909090909091f
#define LMU_IN  (-8.4231266823771690f)   // log(0.9/4096)
#define LMU_BIN (-2.3025850929940457f)   // log(0.1)

// 8 Gauss-Seidel Sinkhorn iterations: contraction factor per full iteration is
// phi^2 = 1/121 (LSE is 1-Lipschitz in sup-norm, each half-update scales by phi).
// ||V_k - V*|| <= 2.6 * 121^-k  ->  k=8 gives ~5e-17, i.e. identical fixed point
// to the reference's 100 iterations within fp32 roundoff.
#define SINK_ITERS 8

// -------------------- helpers --------------------

__device__ __forceinline__ float block_reduce_sum_256(float v) {
    // wave64 butterfly then cross-wave via LDS; result valid on thread 0 only
    #pragma unroll
    for (int off = 32; off > 0; off >>= 1) v += __shfl_down(v, off, 64);
    __shared__ float sb[4];
    if ((threadIdx.x & 63) == 0) sb[threadIdx.x >> 6] = v;
    __syncthreads();
    float r = 0.f;
    if (threadIdx.x == 0) r = sb[0] + sb[1] + sb[2] + sb[3];
    return r;
}

// -------------------- kernels --------------------

// 1/||row|| for both feature matrices. grid = Nn+Mm blocks of 256.
__global__ __launch_bounds__(256) void rownorm_kernel(
    const float* __restrict__ A, const float* __restrict__ B,
    float* __restrict__ rn0, float* __restrict__ rn1) {
    const int row = blockIdx.x;
    const float* p = (row < Nn) ? (A + (size_t)row * Dd)
                                : (B + (size_t)(row - Nn) * Dd);
    float s = 0.f;
    for (int k = threadIdx.x; k < Dd; k += 256) { float x = p[k]; s += x * x; }
    s = block_reduce_sum_256(s);
    if (threadIdx.x == 0) {
        float rn = 1.0f / sqrtf(s);
        if (row < Nn) rn0[row] = rn; else rn1[row - Nn] = rn;
    }
}

// E[i][j] = exp(10 * cos_sim(i,j)) for interior 4096x4096 block.
// 64x64 C-tile per 256-thread block, 4x4 micro-tile, fp32 vector FMA
// (no fp32-input MFMA on CDNA4).
__global__ __launch_bounds__(256) void gemm_exp_kernel(
    const float* __restrict__ A, const float* __restrict__ B,
    const float* __restrict__ rn0, const float* __restrict__ rn1,
    float* __restrict__ E) {
    // k-major LDS tiles: stride 68 floats = 272B (16B aligned rows, <=2-way banks)
    __shared__ __align__(16) float As[16][68];
    __shared__ __align__(16) float Bs[16][68];
    const int tid = threadIdx.x;
    const int tx = tid & 15, ty = tid >> 4;
    const int row0 = blockIdx.y << 6, col0 = blockIdx.x << 6;
    const int r  = tid >> 2;          // 0..63 : tile row/col being staged
    const int kq = (tid & 3) << 2;    // 0,4,8,12 : k sub-offset (float4)
    const float* Ap = A + (size_t)(row0 + r) * Dd + kq;
    const float* Bp = B + (size_t)(col0 + r) * Dd + kq;

    float acc[4][4] = {{0.f}};
    for (int k0 = 0; k0 < Dd; k0 += 16) {
        const float4 av = *(const float4*)(Ap + k0);
        const float4 bv = *(const float4*)(Bp + k0);
        __syncthreads();
        As[kq + 0][r] = av.x; As[kq + 1][r] = av.y;
        As[kq + 2][r] = av.z; As[kq + 3][r] = av.w;
        Bs[kq + 0][r] = bv.x; Bs[kq + 1][r] = bv.y;
        Bs[kq + 2][r] = bv.z; Bs[kq + 3][r] = bv.w;
        __syncthreads();
        #pragma unroll
        for (int kk = 0; kk < 16; ++kk) {
            const float4 a = *(const float4*)&As[kk][ty << 2];
            const float4 b = *(const float4*)&Bs[kk][tx << 2];
            const float ar[4] = {a.x, a.y, a.z, a.w};
            const float br[4] = {b.x, b.y, b.z, b.w};
            #pragma unroll
            for (int ii = 0; ii < 4; ++ii)
                #pragma unroll
                for (int jj = 0; jj < 4; ++jj)
                    acc[ii][jj] = fmaf(ar[ii], br[jj], acc[ii][jj]);
        }
    }
    float s0[4], s1[4];
    #pragma unroll
    for (int i = 0; i < 4; ++i) {
        s0[i] = 10.0f * rn0[row0 + (ty << 2) + i];
        s1[i] = rn1[col0 + (tx << 2) + i];
    }
    #pragma unroll
    for (int i = 0; i < 4; ++i) {
        float* out = E + (size_t)(row0 + (ty << 2) + i) * NP + col0 + (tx << 2);
        #pragma unroll
        for (int j = 0; j < 4; ++j)
            out[j] = expf(s0[i] * s1[j] * acc[i][j]);
    }
}

// Dustbin column (j = Mm) and dustbin row (i = Nn): E = exp(10*bin_score).
__global__ void fill_bins_kernel(float* __restrict__ E,
                                 const float* __restrict__ binp) {
    const float eb = expf(10.0f * binp[0]);
    const int idx = blockIdx.x * 256 + threadIdx.x;
    if (idx < Nn)            E[(size_t)idx * NP + Mm] = eb;          // right col
    else if (idx < Nn + NP)  E[(size_t)Nn * NP + (idx - Nn)] = eb;   // bottom row
}

__global__ void init_w_kernel(float* __restrict__ w) {
    const int j = blockIdx.x * 256 + threadIdx.x;
    if (j < NP) w[j] = 1.0f;   // v = 0 initially
}

// Row sweep: S_i = sum_j E[i][j] * w[j];  eU[i] = exp(phi*(log_mu_i - log S_i)).
// Also zeroes Tb[i] for the following column sweep.
__global__ __launch_bounds__(256) void row_pass_kernel(
    const float* __restrict__ E, const float* __restrict__ w,
    float* __restrict__ eU, float* __restrict__ Tb) {
    const int i = blockIdx.x;
    const float* row = E + (size_t)i * NP;
    float s = 0.f;
    for (int j = threadIdx.x; j < NP; j += 256) s += row[j] * w[j];
    s = block_reduce_sum_256(s);
    if (threadIdx.x == 0) {
        const float lmu = (i < Nn) ? LMU_IN : LMU_BIN;
        eU[i] = expf(PHI * (lmu - logf(s)));
        Tb[i] = 0.f;
    }
}

// Column sweep: Tb[j] += sum over a row-stripe of E[i][j] * eU[i].
// grid (17, 64): 17 column-tiles of 256, 64 row-stripes of 65.
#define ROWS_PER 65
__global__ __launch_bounds__(256) void col_pass_kernel(
    const float* __restrict__ E, const float* __restrict__ eU,
    float* __restrict__ Tb) {
    const int j = blockIdx.x * 256 + threadIdx.x;
    if (j >= NP) return;
    const int r0 = blockIdx.y * ROWS_PER;
    const int r1 = min(r0 + ROWS_PER, NP);
    float s = 0.f;
    for (int r = r0; r < r1; ++r) s += E[(size_t)r * NP + j] * eU[r];
    atomicAdd(&Tb[j], s);
}

__global__ void col_finish_kernel(const float* __restrict__ Tb,
                                  float* __restrict__ w) {
    const int j = blockIdx.x * 256 + threadIdx.x;
    if (j >= NP) return;
    const float lnu = (j < Mm) ? LMU_IN : LMU_BIN;
    w[j] = expf(PHI * (lnu - logf(Tb[j])));
}

// prob[i][j] = E[i][j] * eU[i] * w[j], corner zeroed, in place on d_out.
__global__ __launch_bounds__(256) void finish_kernel(
    float* __restrict__ E, const float* __restrict__ eU,
    const float* __restrict__ w) {
    const int i = blockIdx.x;
    const float s = eU[i];
    float* row = E + (size_t)i * NP;
    for (int j = threadIdx.x; j < NP; j += 256) {
        float v = row[j] * s * w[j];
        if (i == Nn && j == Mm) v = 0.f;
        row[j] = v;
    }
}

// -------------------- launch --------------------

extern "C" void kernel_launch(void* const* d_in, const int* in_sizes, int n_in,
                              void* d_out, int out_size, void* d_ws, size_t ws_size,
                              hipStream_t stream) {
    const float* ft0 = (const float*)d_in[0];
    const float* ft1 = (const float*)d_in[1];
    const float* bin = (const float*)d_in[2];
    float* E = (float*)d_out;          // 4097x4097: holds exp(Z), then prob in place

    float* rn0 = (float*)d_ws;         // [4096]
    float* rn1 = rn0 + Nn;             // [4096]
    float* eU  = rn1 + Mm;             // [4097] e^{lmba*u}
    float* w   = eU + NP;              // [4097] e^{lmba*v}
    float* Tb  = w + NP;               // [4097] column-sum accumulator

    rownorm_kernel<<<Nn + Mm, 256, 0, stream>>>(ft0, ft1, rn0, rn1);
    gemm_exp_kernel<<<dim3(64, 64), 256, 0, stream>>>(ft0, ft1, rn0, rn1, E);
    fill_bins_kernel<<<(Nn + NP + 255) / 256, 256, 0, stream>>>(E, bin);
    init_w_kernel<<<(NP + 255) / 256, 256, 0, stream>>>(w);

    for (int it = 0; it < SINK_ITERS; ++it) {
        row_pass_kernel<<<NP, 256, 0, stream>>>(E, w, eU, Tb);
        col_pass_kernel<<<dim3((NP + 255) / 256, 64), 256, 0, stream>>>(E, eU, Tb);
        col_finish_kernel<<<(NP + 255) / 256, 256, 0, stream>>>(Tb, w);
    }

    finish_kernel<<<NP, 256, 0, stream>>>(E, eU, w);
}

// Round 2
// 284.396 us; speedup vs baseline: 2.3787x; 2.3787x over previous
//
#include <hip/hip_runtime.h>
#include <math.h>

// Problem constants (fixed by the reference)
#define Nn 4096
#define Mm 4096
#define Dd 512
#define NP 4097            // N+1 == M+1 (augmented with dustbin)
#define NPB 4104           // padded bf16-E leading dim (16B-aligned rows: 4104*2 = 8208 = 16*513)

// phi = REG_KL / (REG_KL + REG) = 0.01/0.11 ; lmba = 10
#define PHI 0.09090909090909091f
#define LMU_IN  (-8.4231266823771690f)   // log(0.9/4096)
#define LMU_BIN (-2.3025850929940457f)   // log(0.1)

// Contraction per full Gauss-Seidel iteration is phi^2 = 1/121.
// ||v0 - v*|| <= 0.16  ->  5 iters: 0.16*121^-5 ~ 6e-12, below fp32 noise.
#define SINK_ITERS 5

typedef __attribute__((ext_vector_type(8))) __bf16 bf16x8;
typedef __attribute__((ext_vector_type(4))) float  f32x4;

// -------------------- helpers --------------------

__device__ __forceinline__ float block_reduce_sum_256(float v) {
    #pragma unroll
    for (int off = 32; off > 0; off >>= 1) v += __shfl_down(v, off, 64);
    __shared__ float sb[4];
    if ((threadIdx.x & 63) == 0) sb[threadIdx.x >> 6] = v;
    __syncthreads();
    float r = 0.f;
    if (threadIdx.x == 0) r = sb[0] + sb[1] + sb[2] + sb[3];
    return r;
}

__device__ __forceinline__ float block_allreduce_sum_256(float v) {
    #pragma unroll
    for (int off = 32; off > 0; off >>= 1) v += __shfl_down(v, off, 64);
    __shared__ float sb[4];
    if ((threadIdx.x & 63) == 0) sb[threadIdx.x >> 6] = v;
    __syncthreads();
    return sb[0] + sb[1] + sb[2] + sb[3];
}

__device__ __forceinline__ float bf_lo(unsigned u) { return __uint_as_float(u << 16); }
__device__ __forceinline__ float bf_hi(unsigned u) { return __uint_as_float(u & 0xffff0000u); }

// async global->LDS, 16B per lane. LDS dest must be wave-uniform base + lane*16.
__device__ __forceinline__ void load_lds16(const __bf16* g, __bf16* l) {
    __builtin_amdgcn_global_load_lds(
        (__attribute__((address_space(1))) void*)g,
        (__attribute__((address_space(3))) void*)l,
        16, 0, 0);
}

// ==================== FAST PATH (bf16 MFMA) ====================

// Normalize rows of ft0/ft1 and emit bf16. grid = Nn+Mm blocks of 256.
__global__ __launch_bounds__(256) void normalize_bf16_kernel(
    const float* __restrict__ F0, const float* __restrict__ F1,
    __bf16* __restrict__ A, __bf16* __restrict__ B) {
    const int row = blockIdx.x;
    const float* src = (row < Nn) ? (F0 + (size_t)row * Dd)
                                  : (F1 + (size_t)(row - Nn) * Dd);
    __bf16* dst = (row < Nn) ? (A + (size_t)row * Dd)
                             : (B + (size_t)(row - Nn) * Dd);
    const float2 x = ((const float2*)src)[threadIdx.x];
    float s = block_allreduce_sum_256(x.x * x.x + x.y * x.y);
    const float rn = rsqrtf(s);
    dst[2 * threadIdx.x]     = (__bf16)(x.x * rn);
    dst[2 * threadIdx.x + 1] = (__bf16)(x.y * rn);
}

// E = exp(10 * A B^T) for the interior 4096x4096 block.
// 128x128 tile / 256 threads (4 waves, 2x2), BK=32, 16x16x32 bf16 MFMA,
// global_load_lds width-16 staging (m97 structure).
__global__ __launch_bounds__(256) void gemm_mfma_kernel(
    const __bf16* __restrict__ A, const __bf16* __restrict__ B,
    float* __restrict__ E, __bf16* __restrict__ Ebf) {
    __shared__ __align__(16) __bf16 As[128 * 32];
    __shared__ __align__(16) __bf16 Bs[128 * 32];
    const int tid = threadIdx.x;
    const int l = tid & 63, wv = tid >> 6;
    const int wm = wv >> 1, wn = wv & 1;
    const int ln = l & 15, lq = l >> 4;
    const int row0 = blockIdx.y << 7, col0 = blockIdx.x << 7;

    f32x4 acc[4][4];
    #pragma unroll
    for (int i = 0; i < 4; ++i)
        #pragma unroll
        for (int j = 0; j < 4; ++j) acc[i][j] = (f32x4){0.f, 0.f, 0.f, 0.f};

    // staging: chunk c*256+tid -> tile row chunk>>2, k-offset (chunk&3)*8
    const int ch0 = tid, ch1 = 256 + tid;
    const __bf16* a0 = A + (size_t)(row0 + (ch0 >> 2)) * Dd + ((ch0 & 3) << 3);
    const __bf16* a1 = A + (size_t)(row0 + (ch1 >> 2)) * Dd + ((ch1 & 3) << 3);
    const __bf16* b0 = B + (size_t)(col0 + (ch0 >> 2)) * Dd + ((ch0 & 3) << 3);
    const __bf16* b1 = B + (size_t)(col0 + (ch1 >> 2)) * Dd + ((ch1 & 3) << 3);
    __bf16* lA0 = &As[ch0 * 8]; __bf16* lA1 = &As[ch1 * 8];
    __bf16* lB0 = &Bs[ch0 * 8]; __bf16* lB1 = &Bs[ch1 * 8];

    for (int k0 = 0; k0 < Dd; k0 += 32) {
        __syncthreads();
        load_lds16(a0 + k0, lA0);
        load_lds16(a1 + k0, lA1);
        load_lds16(b0 + k0, lB0);
        load_lds16(b1 + k0, lB1);
        __syncthreads();
        bf16x8 af[4], bfr[4];
        #pragma unroll
        for (int mi = 0; mi < 4; ++mi)
            af[mi] = *(const bf16x8*)&As[(wm * 64 + mi * 16 + ln) * 32 + lq * 8];
        #pragma unroll
        for (int ni = 0; ni < 4; ++ni)
            bfr[ni] = *(const bf16x8*)&Bs[(wn * 64 + ni * 16 + ln) * 32 + lq * 8];
        #pragma unroll
        for (int mi = 0; mi < 4; ++mi)
            #pragma unroll
            for (int ni = 0; ni < 4; ++ni)
                acc[mi][ni] = __builtin_amdgcn_mfma_f32_16x16x32_bf16(
                    af[mi], bfr[ni], acc[mi][ni], 0, 0, 0);
    }

    // C/D layout (m89-verified): col = lane&15, row = (lane>>4)*4 + reg
    #pragma unroll
    for (int mi = 0; mi < 4; ++mi) {
        #pragma unroll
        for (int r = 0; r < 4; ++r) {
            const int gi = row0 + wm * 64 + mi * 16 + lq * 4 + r;
            float*  eRow = E   + (size_t)gi * NP  + col0 + wn * 64 + ln;
            __bf16* bRow = Ebf + (size_t)gi * NPB + col0 + wn * 64 + ln;
            #pragma unroll
            for (int ni = 0; ni < 4; ++ni) {
                const float e = __expf(10.0f * acc[mi][ni][r]);
                eRow[ni * 16] = e;
                bRow[ni * 16] = (__bf16)e;
            }
        }
    }
}

// Dustbin col (j=Mm) and row (i=Nn) into both fp32 and bf16 E.
__global__ void fill_bins2_kernel(float* __restrict__ E, __bf16* __restrict__ Ebf,
                                  const float* __restrict__ binp) {
    const float eb = __expf(10.0f * binp[0]);
    const __bf16 ebb = (__bf16)eb;
    const int idx = blockIdx.x * 256 + threadIdx.x;
    if (idx < Nn) {
        E[(size_t)idx * NP + Mm] = eb;
        Ebf[(size_t)idx * NPB + Mm] = ebb;
    } else if (idx < Nn + NP) {
        const int j = idx - Nn;
        E[(size_t)Nn * NP + j] = eb;
        Ebf[(size_t)Nn * NPB + j] = ebb;
    }
}

// Row sweep over bf16 E: S_i = sum_j E[i][j]*w[j]; eU[i]=exp(phi*(lmu-log S)).
__global__ __launch_bounds__(256) void row_pass_bf_kernel(
    const __bf16* __restrict__ Ebf, const float* __restrict__ w,
    float* __restrict__ eU, float* __restrict__ Tb) {
    const int i = blockIdx.x;
    const unsigned short* row = (const unsigned short*)(Ebf + (size_t)i * NPB);
    float s = 0.f;
    #pragma unroll
    for (int c = 0; c < 2; ++c) {
        const int chunk = c * 256 + threadIdx.x;      // 0..511 -> cols chunk*8..+8
        const uint4 u = *(const uint4*)(row + chunk * 8);
        const float4 w0 = *(const float4*)(w + chunk * 8);
        const float4 w1 = *(const float4*)(w + chunk * 8 + 4);
        s += bf_lo(u.x) * w0.x + bf_hi(u.x) * w0.y
           + bf_lo(u.y) * w0.z + bf_hi(u.y) * w0.w
           + bf_lo(u.z) * w1.x + bf_hi(u.z) * w1.y
           + bf_lo(u.w) * w1.z + bf_hi(u.w) * w1.w;
    }
    if (threadIdx.x == 0)
        s += (float)Ebf[(size_t)i * NPB + Mm] * w[Mm];   // tail col 4096
    s = block_reduce_sum_256(s);
    if (threadIdx.x == 0) {
        const float lmu = (i < Nn) ? LMU_IN : LMU_BIN;
        eU[i] = __expf(PHI * (lmu - __logf(s)));
        Tb[i] = 0.f;
    }
}

// Column sweep over bf16 E: Tb[j] += stripe-sum of E[i][j]*eU[i].
#define CROWS 32
__global__ __launch_bounds__(256) void col_pass_bf_kernel(
    const __bf16* __restrict__ Ebf, const float* __restrict__ eU,
    float* __restrict__ Tb) {
    const int j0 = blockIdx.x * 512 + threadIdx.x * 2;
    if (j0 > Mm) return;           // j0 even; col j0 must exist
    const int r0 = blockIdx.y * CROWS;
    const int r1 = min(r0 + CROWS, NP);
    const unsigned short* base = (const unsigned short*)Ebf;
    float s0 = 0.f, s1 = 0.f;
    for (int r = r0; r < r1; ++r) {
        const unsigned u = *(const unsigned*)(base + (size_t)r * NPB + j0);
        const float ev = eU[r];
        s0 += bf_lo(u) * ev;
        s1 += bf_hi(u) * ev;
    }
    atomicAdd(&Tb[j0], s0);
    if (j0 + 1 < NP) atomicAdd(&Tb[j0 + 1], s1);
}

__global__ void col_finish_kernel(const float* __restrict__ Tb,
                                  float* __restrict__ w) {
    const int j = blockIdx.x * 256 + threadIdx.x;
    if (j >= NP) return;
    const float lnu = (j < Mm) ? LMU_IN : LMU_BIN;
    w[j] = __expf(PHI * (lnu - __logf(Tb[j])));
}

__global__ void init_w_kernel(float* __restrict__ w) {
    const int j = blockIdx.x * 256 + threadIdx.x;
    if (j < NP) w[j] = 1.0f;
}

// prob[i][j] = E[i][j]*eU[i]*w[j] in place on fp32 E (d_out), corner zeroed.
__global__ __launch_bounds__(256) void finish_kernel(
    float* __restrict__ E, const float* __restrict__ eU,
    const float* __restrict__ w) {
    const int i = blockIdx.x;
    const float s = eU[i];
    float* row = E + (size_t)i * NP;
    for (int j = threadIdx.x; j < NP; j += 256) {
        float v = row[j] * s * w[j];
        if (i == Nn && j == Mm) v = 0.f;
        row[j] = v;
    }
}

// ==================== FALLBACK PATH (fp32, round-1 proven) ====================

__global__ __launch_bounds__(256) void rownorm_kernel(
    const float* __restrict__ A, const float* __restrict__ B,
    float* __restrict__ rn0, float* __restrict__ rn1) {
    const int row = blockIdx.x;
    const float* p = (row < Nn) ? (A + (size_t)row * Dd)
                                : (B + (size_t)(row - Nn) * Dd);
    float s = 0.f;
    for (int k = threadIdx.x; k < Dd; k += 256) { float x = p[k]; s += x * x; }
    s = block_reduce_sum_256(s);
    if (threadIdx.x == 0) {
        float rn = 1.0f / sqrtf(s);
        if (row < Nn) rn0[row] = rn; else rn1[row - Nn] = rn;
    }
}

__global__ __launch_bounds__(256) void gemm_exp_kernel(
    const float* __restrict__ A, const float* __restrict__ B,
    const float* __restrict__ rn0, const float* __restrict__ rn1,
    float* __restrict__ E) {
    __shared__ __align__(16) float As[16][68];
    __shared__ __align__(16) float Bs[16][68];
    const int tid = threadIdx.x;
    const int tx = tid & 15, ty = tid >> 4;
    const int row0 = blockIdx.y << 6, col0 = blockIdx.x << 6;
    const int r  = tid >> 2;
    const int kq = (tid & 3) << 2;
    const float* Ap = A + (size_t)(row0 + r) * Dd + kq;
    const float* Bp = B + (size_t)(col0 + r) * Dd + kq;

    float acc[4][4] = {{0.f}};
    for (int k0 = 0; k0 < Dd; k0 += 16) {
        const float4 av = *(const float4*)(Ap + k0);
        const float4 bv = *(const float4*)(Bp + k0);
        __syncthreads();
        As[kq + 0][r] = av.x; As[kq + 1][r] = av.y;
        As[kq + 2][r] = av.z; As[kq + 3][r] = av.w;
        Bs[kq + 0][r] = bv.x; Bs[kq + 1][r] = bv.y;
        Bs[kq + 2][r] = bv.z; Bs[kq + 3][r] = bv.w;
        __syncthreads();
        #pragma unroll
        for (int kk = 0; kk < 16; ++kk) {
            const float4 a = *(const float4*)&As[kk][ty << 2];
            const float4 b = *(const float4*)&Bs[kk][tx << 2];
            const float ar[4] = {a.x, a.y, a.z, a.w};
            const float br[4] = {b.x, b.y, b.z, b.w};
            #pragma unroll
            for (int ii = 0; ii < 4; ++ii)
                #pragma unroll
                for (int jj = 0; jj < 4; ++jj)
                    acc[ii][jj] = fmaf(ar[ii], br[jj], acc[ii][jj]);
        }
    }
    float s0[4], s1[4];
    #pragma unroll
    for (int i = 0; i < 4; ++i) {
        s0[i] = 10.0f * rn0[row0 + (ty << 2) + i];
        s1[i] = rn1[col0 + (tx << 2) + i];
    }
    #pragma unroll
    for (int i = 0; i < 4; ++i) {
        float* out = E + (size_t)(row0 + (ty << 2) + i) * NP + col0 + (tx << 2);
        #pragma unroll
        for (int j = 0; j < 4; ++j)
            out[j] = expf(s0[i] * s1[j] * acc[i][j]);
    }
}

__global__ void fill_bins_kernel(float* __restrict__ E,
                                 const float* __restrict__ binp) {
    const float eb = expf(10.0f * binp[0]);
    const int idx = blockIdx.x * 256 + threadIdx.x;
    if (idx < Nn)            E[(size_t)idx * NP + Mm] = eb;
    else if (idx < Nn + NP)  E[(size_t)Nn * NP + (idx - Nn)] = eb;
}

__global__ __launch_bounds__(256) void row_pass_kernel(
    const float* __restrict__ E, const float* __restrict__ w,
    float* __restrict__ eU, float* __restrict__ Tb) {
    const int i = blockIdx.x;
    const float* row = E + (size_t)i * NP;
    float s = 0.f;
    for (int j = threadIdx.x; j < NP; j += 256) s += row[j] * w[j];
    s = block_reduce_sum_256(s);
    if (threadIdx.x == 0) {
        const float lmu = (i < Nn) ? LMU_IN : LMU_BIN;
        eU[i] = expf(PHI * (lmu - logf(s)));
        Tb[i] = 0.f;
    }
}

#define ROWS_PER 65
__global__ __launch_bounds__(256) void col_pass_kernel(
    const float* __restrict__ E, const float* __restrict__ eU,
    float* __restrict__ Tb) {
    const int j = blockIdx.x * 256 + threadIdx.x;
    if (j >= NP) return;
    const int r0 = blockIdx.y * ROWS_PER;
    const int r1 = min(r0 + ROWS_PER, NP);
    float s = 0.f;
    for (int r = r0; r < r1; ++r) s += E[(size_t)r * NP + j] * eU[r];
    atomicAdd(&Tb[j], s);
}

// -------------------- launch --------------------

extern "C" void kernel_launch(void* const* d_in, const int* in_sizes, int n_in,
                              void* d_out, int out_size, void* d_ws, size_t ws_size,
                              hipStream_t stream) {
    const float* ft0 = (const float*)d_in[0];
    const float* ft1 = (const float*)d_in[1];
    const float* bin = (const float*)d_in[2];
    float* E = (float*)d_out;          // 4097x4097 fp32: exp(Z), then prob in place

    // fast-path ws layout (16B-aligned segments)
    const size_t ABF_B  = (size_t)Nn * Dd * 2;          // 4,194,304
    const size_t EBF_B  = (size_t)NP * NPB * 2;         // 33,628,176
    const size_t VEC_B  = 16400;                        // 4097 floats, padded
    const size_t FAST_WS = 2 * ABF_B + EBF_B + 3 * VEC_B;

    if (ws_size >= FAST_WS) {
        __bf16* Abf = (__bf16*)d_ws;
        __bf16* Bbf = (__bf16*)((char*)d_ws + ABF_B);
        __bf16* Ebf = (__bf16*)((char*)d_ws + 2 * ABF_B);
        float*  eU  = (float*)((char*)d_ws + 2 * ABF_B + EBF_B);
        float*  w   = (float*)((char*)d_ws + 2 * ABF_B + EBF_B + VEC_B);
        float*  Tb  = (float*)((char*)d_ws + 2 * ABF_B + EBF_B + 2 * VEC_B);

        normalize_bf16_kernel<<<Nn + Mm, 256, 0, stream>>>(ft0, ft1, Abf, Bbf);
        gemm_mfma_kernel<<<dim3(32, 32), 256, 0, stream>>>(Abf, Bbf, E, Ebf);
        fill_bins2_kernel<<<(Nn + NP + 255) / 256, 256, 0, stream>>>(E, Ebf, bin);
        init_w_kernel<<<(NP + 255) / 256, 256, 0, stream>>>(w);

        for (int it = 0; it < SINK_ITERS; ++it) {
            row_pass_bf_kernel<<<NP, 256, 0, stream>>>(Ebf, w, eU, Tb);
            col_pass_bf_kernel<<<dim3(9, (NP + CROWS - 1) / CROWS), 256, 0, stream>>>(Ebf, eU, Tb);
            col_finish_kernel<<<(NP + 255) / 256, 256, 0, stream>>>(Tb, w);
        }
        finish_kernel<<<NP, 256, 0, stream>>>(E, eU, w);
    } else {
        float* rn0 = (float*)d_ws;
        float* rn1 = rn0 + Nn;
        float* eU  = rn1 + Mm;
        float* w   = eU + NP;
        float* Tb  = w + NP;

        rownorm_kernel<<<Nn + Mm, 256, 0, stream>>>(ft0, ft1, rn0, rn1);
        gemm_exp_kernel<<<dim3(64, 64), 256, 0, stream>>>(ft0, ft1, rn0, rn1, E);
        fill_bins_kernel<<<(Nn + NP + 255) / 256, 256, 0, stream>>>(E, bin);
        init_w_kernel<<<(NP + 255) / 256, 256, 0, stream>>>(w);

        for (int it = 0; it < SINK_ITERS; ++it) {
            row_pass_kernel<<<NP, 256, 0, stream>>>(E, w, eU, Tb);
            col_pass_kernel<<<dim3((NP + 255) / 256, 64), 256, 0, stream>>>(E, eU, Tb);
            col_finish_kernel<<<(NP + 255) / 256, 256, 0, stream>>>(Tb, w);
        }
        finish_kernel<<<NP, 256, 0, stream>>>(E, eU, w);
    }
}